// Round 7
// baseline (141.135 us; speedup 1.0000x reference)
//
#include <hip/hip_runtime.h>

// APG_Linear: out[b] = ((inp[b] @ U) @ W_b) @ V + bias
//   B=131072, IN=128, OUT=128, RANK=32, all f32. Memory-bound (671 MB, ~102 us floor).
// R6 = R5 with the compile fix: h2_t is __fp16-based (what cvt_pkrtz/fdot2
// actually use on this clang), bitcasts via memcpy.
// R5 theory (untested): latency/TLP attack —
//   1. V as packed f16 pairs (32 VGPRs, was 64 f32) + v_dot2_f32_f16.
//   2. __launch_bounds__(256,4): VGPR <= 128 -> 4 waves/SIMD (was ~2).
//   3. Depth-2 W/x prefetch, two explicit buffers, unrolled x2 (static idx).

constexpr int RANK  = 32;
constexpr int BLOCK = 256;            // 4 waves/block
constexpr int WPB   = BLOCK / 64;
constexpr int GRID  = 1024;           // 4 blocks/CU
constexpr int NWAVES = GRID * WPB;    // 4096 waves -> 32 rows/wave at B=131072

typedef int    i2_t __attribute__((ext_vector_type(2)));
typedef __fp16 h2_t __attribute__((ext_vector_type(2)));

#define USE_DOT2 (__has_builtin(__builtin_amdgcn_fdot2) && __has_builtin(__builtin_amdgcn_cvt_pkrtz))

// --- VALU-pipe butterfly stages (keep these OFF the LDS pipe) ---
__device__ __forceinline__ float red_xor8(float v) {
#if __has_builtin(__builtin_amdgcn_update_dpp)
    int m = __builtin_amdgcn_update_dpp(0, __float_as_int(v), 0x128, 0xf, 0xf, true);
    return v + __int_as_float(m);
#else
    return v + __shfl_xor(v, 8, 64);
#endif
}
__device__ __forceinline__ float red_xor16(float v) {
#if __has_builtin(__builtin_amdgcn_permlane16_swap)
    i2_t r = __builtin_amdgcn_permlane16_swap(__float_as_int(v), __float_as_int(v),
                                              false, false);
    return __int_as_float(r.x) + __int_as_float(r.y);
#else
    return v + __shfl_xor(v, 16, 64);
#endif
}
__device__ __forceinline__ float red_xor32(float v) {
#if __has_builtin(__builtin_amdgcn_permlane32_swap)
    i2_t r = __builtin_amdgcn_permlane32_swap(__float_as_int(v), __float_as_int(v),
                                              false, false);
    return __int_as_float(r.x) + __int_as_float(r.y);
#else
    return v + __shfl_xor(v, 32, 64);
#endif
}
__device__ __forceinline__ float red_g(float v) {
    return red_xor32(red_xor16(red_xor8(v)));
}

__device__ __forceinline__ h2_t rl_h2(int packed, int srclane) {
    int i = __builtin_amdgcn_readlane(packed, srclane);
    h2_t r; __builtin_memcpy(&r, &i, 4);
    return r;
}
__device__ __forceinline__ int pack_h2(float a, float b) {
#if USE_DOT2
    auto p = __builtin_amdgcn_cvt_pkrtz(a, b);   // __fp16 x2 on this clang
    int i; __builtin_memcpy(&i, &p, 4);
    return i;
#else
    return 0;
#endif
}

__global__ __launch_bounds__(BLOCK, 4)   // VGPR <= 128 -> 4 waves/SIMD
void apg_linear_kernel(const float* __restrict__ inp,
                       const float* __restrict__ gw,
                       const float* __restrict__ U,
                       const float* __restrict__ V,
                       const float* __restrict__ bias,
                       float* __restrict__ out,
                       int nrows)
{
    __shared__ float4 u4s[1024];        // U staged: 128x32 f32 = 16 KiB
    __shared__ float  hbuf[WPB][RANK];  // per-wave h park (128 B each)

    const int tid  = threadIdx.x;
    const int lane = tid & 63;
    const int wid  = tid >> 6;
    const int g    = lane >> 3;         // 0..7

    // ---- stage U into LDS (flat float4 layout: u4s[f] = U[4f..4f+3]) ----
    #pragma unroll
    for (int j = 0; j < 4; ++j)
        u4s[j * BLOCK + tid] = reinterpret_cast<const float4*>(U)[j * BLOCK + tid];
    __syncthreads();

    // ---- V packed as f16 r-pairs: lane owns out cols j0=2*lane, j1=2*lane+1
    //      v2a[s] = (V[2s][j0], V[2s+1][j0]); v2b[s] likewise for j1.
#if USE_DOT2
    h2_t v2a[16], v2b[16];
    #pragma unroll
    for (int s = 0; s < 16; ++s) {
        const float2 r0 = reinterpret_cast<const float2*>(V + (2*s)     * 128)[lane];
        const float2 r1 = reinterpret_cast<const float2*>(V + (2*s + 1) * 128)[lane];
        v2a[s] = h2_t{(__fp16)r0.x, (__fp16)r1.x};
        v2b[s] = h2_t{(__fp16)r0.y, (__fp16)r1.y};
    }
#else
    float2 v2[RANK];
    #pragma unroll
    for (int r = 0; r < RANK; ++r)
        v2[r] = reinterpret_cast<const float2*>(V + r * 128)[lane];
#endif
    const float2 b2 = reinterpret_cast<const float2*>(bias)[lane];

    float* hw = hbuf[wid];

    const int wave0 = blockIdx.x * WPB + wid;
    const int iters = (nrows + NWAVES - 1) / NWAVES;   // 32 at B=131072

    // ---- depth-2 prefetch: two explicit buffer sets (static indices) ----
    float  x0A = 0.f, x1A = 0.f, x0B = 0.f, x1B = 0.f;
    float4 wA[4] = {}, wB[4] = {};

    const int rA0 = wave0;
    const int rB0 = wave0 + NWAVES;
    if (rA0 < nrows) {
        x0A = inp[rA0 * 128 + lane];
        x1A = inp[rA0 * 128 + 64 + lane];
        const float4* wp = reinterpret_cast<const float4*>(gw) + rA0 * 256;
        #pragma unroll
        for (int t = 0; t < 4; ++t) wA[t] = wp[t * 64 + lane];
    }
    if (rB0 < nrows) {
        x0B = inp[rB0 * 128 + lane];
        x1B = inp[rB0 * 128 + 64 + lane];
        const float4* wp = reinterpret_cast<const float4*>(gw) + rB0 * 256;
        #pragma unroll
        for (int t = 0; t < 4; ++t) wB[t] = wp[t * 64 + lane];
    }

    // process one row from (x0,x1,w4); then refill that buffer from prow
    auto process = [&](int row, float& x0, float& x1, float4 (&w4)[4], int prow) {
        // ---- step 1: h = inp_row @ U ----
        float h1a[4] = {0.f, 0.f, 0.f, 0.f};
        #pragma unroll
        for (int t = 0; t < 16; ++t) {
            const float xs = (t < 8) ? x0 : x1;
            const float xi = __shfl(xs, (t & 7) * 8 + g, 64);
            const float4 u = u4s[t * 64 + lane];
            h1a[0] = fmaf(xi, u.x, h1a[0]);
            h1a[1] = fmaf(xi, u.y, h1a[1]);
            h1a[2] = fmaf(xi, u.z, h1a[2]);
            h1a[3] = fmaf(xi, u.w, h1a[3]);
        }
        #pragma unroll
        for (int k = 0; k < 4; ++k) h1a[k] = red_g(h1a[k]);   // VALU butterfly
        if (lane < 8)
            reinterpret_cast<float4*>(hw)[lane] =
                make_float4(h1a[0], h1a[1], h1a[2], h1a[3]);

        // ---- step 2: h2 = h @ W_b (last consumer of w4/x0/x1) ----
        float h2a[4] = {0.f, 0.f, 0.f, 0.f};
        #pragma unroll
        for (int t = 0; t < 4; ++t) {
            const float hi = hw[t * 8 + g];                // broadcast read
            h2a[0] = fmaf(hi, w4[t].x, h2a[0]);
            h2a[1] = fmaf(hi, w4[t].y, h2a[1]);
            h2a[2] = fmaf(hi, w4[t].z, h2a[2]);
            h2a[3] = fmaf(hi, w4[t].w, h2a[3]);
        }

        // ---- prefetch row+2*NWAVES into the buffer just freed ----
        if (prow < nrows) {
            x0 = inp[prow * 128 + lane];
            x1 = inp[prow * 128 + 64 + lane];
            const float4* wp = reinterpret_cast<const float4*>(gw) + prow * 256;
            #pragma unroll
            for (int t = 0; t < 4; ++t) w4[t] = wp[t * 64 + lane];
        }

        #pragma unroll
        for (int k = 0; k < 4; ++k) h2a[k] = red_g(h2a[k]);   // VALU butterfly

        // ---- step 3: out_row = h2 @ V + bias ----
        float o0 = b2.x, o1 = b2.y;
#if USE_DOT2
        const int h2p0 = pack_h2(h2a[0], h2a[1]);  // (h2[4c],   h2[4c+1]) @ lane c
        const int h2p1 = pack_h2(h2a[2], h2a[3]);  // (h2[4c+2], h2[4c+3]) @ lane c
        #pragma unroll
        for (int c = 0; c < 8; ++c) {
            const h2_t p0 = rl_h2(h2p0, c);        // r-pair s = 2c
            const h2_t p1 = rl_h2(h2p1, c);        // r-pair s = 2c+1
            o0 = __builtin_amdgcn_fdot2(p0, v2a[2*c],     o0, false);
            o1 = __builtin_amdgcn_fdot2(p0, v2b[2*c],     o1, false);
            o0 = __builtin_amdgcn_fdot2(p1, v2a[2*c + 1], o0, false);
            o1 = __builtin_amdgcn_fdot2(p1, v2b[2*c + 1], o1, false);
        }
#else
        #pragma unroll
        for (int r = 0; r < RANK; ++r) {
            const float h2r = __uint_as_float(
                __builtin_amdgcn_readlane(__float_as_uint(h2a[r & 3]), r >> 2));
            o0 = fmaf(h2r, v2[r].x, o0);
            o1 = fmaf(h2r, v2[r].y, o1);
        }
#endif
        reinterpret_cast<float2*>(out)[row * 64 + lane] = make_float2(o0, o1);
    };

    for (int it = 0; it < iters; it += 2) {
        const int rowA = wave0 + it * NWAVES;
        const int rowB = rowA + NWAVES;
        if (rowA >= nrows) break;
        process(rowA, x0A, x1A, wA, rowA + 2 * NWAVES);
        if (rowB >= nrows) break;
        process(rowB, x0B, x1B, wB, rowB + 2 * NWAVES);
    }
}

extern "C" void kernel_launch(void* const* d_in, const int* in_sizes, int n_in,
                              void* d_out, int out_size, void* d_ws, size_t ws_size,
                              hipStream_t stream)
{
    const float* inp  = (const float*)d_in[0];
    const float* gw   = (const float*)d_in[1];
    const float* U    = (const float*)d_in[2];
    const float* V    = (const float*)d_in[3];
    const float* bias = (const float*)d_in[4];
    float* out = (float*)d_out;
    const int nrows = in_sizes[0] / 128;   // B = 131072

    apg_linear_kernel<<<GRID, BLOCK, 0, stream>>>(inp, gw, U, V, bias, out, nrows);
}